// Round 1
// baseline (333.918 us; speedup 1.0000x reference)
//
#include <hip/hip_runtime.h>

#define TOKENS 32768
#define DIN 1024
#define DOUT 1024
#define RANK 16
#define SCALE1 0.5f
#define SCALE2 1.0f

// R6: 256x256 tile, BK=64, 8 waves, 8-phase schedule (4 quadrant phases per
// K-tile, 2 K-tiles per unrolled iter). Raw s_barrier (asm, "memory") so the
// global_load_lds prefetch issued in phases 0-1 stays in flight across the
// phase barriers; single vmcnt(0) drain per K-tile, ~3 phases after issue.
#define BM 256
#define BN 256
#define BK 64
#define KTILES (DIN / BK)  // 16

typedef __bf16 bf16x8 __attribute__((ext_vector_type(8)));
typedef float f32x4 __attribute__((ext_vector_type(4)));

// Async global->LDS, 16B per lane. LDS dest is wave-uniform base + lane*16.
__device__ __forceinline__ void load_lds16(const void* gptr, void* lptr) {
    __builtin_amdgcn_global_load_lds(
        (__attribute__((address_space(1))) void*)gptr,
        (__attribute__((address_space(3))) void*)lptr, 16, 0, 0);
}

// ---------------------------------------------------------------------------
// Kernel 1: Weff = W + 0.5*B1@A1 + 1.0*B2@A2, cast to bf16.  [DOUT, DIN]
// ---------------------------------------------------------------------------
__global__ void weff_kernel(const float* __restrict__ W, const float* __restrict__ A1,
                            const float* __restrict__ B1, const float* __restrict__ A2,
                            const float* __restrict__ B2, __bf16* __restrict__ Weff) {
    int idx = blockIdx.x * blockDim.x + threadIdx.x;  // over DOUT*DIN
    int o = idx >> 10;
    int i = idx & 1023;
    float s1 = 0.f, s2 = 0.f;
#pragma unroll
    for (int r = 0; r < RANK; ++r) {
        s1 += B1[o * RANK + r] * A1[r * DIN + i];
        s2 += B2[o * RANK + r] * A2[r * DIN + i];
    }
    Weff[idx] = (__bf16)(W[idx] + SCALE1 * s1 + SCALE2 * s2);
}

// ---------------------------------------------------------------------------
// Kernel 2: x fp32 -> bf16, 8 elems/thread, 16B stores. Streaming-bound ~30us;
// fusing into the GEMM exposed HBM latency on the critical path (R4: 250us).
// ---------------------------------------------------------------------------
__global__ void cvt_x_kernel(const float* __restrict__ x, __bf16* __restrict__ xb) {
    int i = (blockIdx.x * blockDim.x + threadIdx.x) * 8;
    float4 a = *(const float4*)(x + i);
    float4 b = *(const float4*)(x + i + 4);
    bf16x8 v;
    v[0] = (__bf16)a.x; v[1] = (__bf16)a.y; v[2] = (__bf16)a.z; v[3] = (__bf16)a.w;
    v[4] = (__bf16)b.x; v[5] = (__bf16)b.y; v[6] = (__bf16)b.z; v[7] = (__bf16)b.w;
    *(bf16x8*)(xb + i) = v;
}

// ---------------------------------------------------------------------------
// Kernel 3: out[M,N] = A[M,K] @ Bw[N,K]^T + bias.  256x256 tile, 8-phase.
//
// LDS layout per half-tile (128 rows x 64 bf16): row-major, 8 chunks of 16B
// per row, phys_chunk = logical_chunk ^ (row & 7). global_load_lds writes
// linearly (lane l -> row l>>3, phys chunk l&7 of a 1024B slab), so the
// inverse swizzle is applied to the per-lane GLOBAL source address and the
// same XOR on the ds_read side (both-sides-or-neither rule).
// ds_read_b128 frag pattern: row ≡ lane&15 (mod 16), chunk = ksub*4+(lane>>4)
// -> phys = chunk ^ (lane&7): max 2 lanes per bank-quad per quarter-wave =
// conflict-free (same class of swizzle measured 0 conflicts at BK=32).
// ---------------------------------------------------------------------------
__global__ __launch_bounds__(512, 2) void gemm_bt_kernel(
    const __bf16* __restrict__ A,   // [TOKENS, DIN] bf16
    const __bf16* __restrict__ Bw,  // [DOUT, DIN] bf16
    const float* __restrict__ bias, float* __restrict__ C) {
    __shared__ alignas(16) __bf16 lsA[2][2][128 * BK];  // [buf][half] 2x2x16KB
    __shared__ alignas(16) __bf16 lsB[2][2][128 * BK];  // total 128 KiB

    const int tid = threadIdx.x;
    const int wave = tid >> 6;
    const int lane = tid & 63;

    // XCD-aware swizzle: 512 blocks = 8 xcds x 64 (bijective). Within an xcd:
    // 16 m-tiles x 4 n-tiles, n fastest, so the 4 blocks sharing an x m-tile
    // are temporally adjacent on ONE xcd and Weff (2MB) stays L2-resident.
    const int l = blockIdx.x;
    const int xcd = l & 7;
    const int s = l >> 3;
    const int m0 = (xcd * 16 + (s >> 2)) * BM;
    const int n0 = (s & 3) * BN;

    const int wm = wave >> 2;  // 0..1  (M half: 128 rows)
    const int wn = wave & 3;   // 0..3  (N quarter: 64 cols)

    // Staging: per call a wave fills one 1024B slab (8 rows x 64 cols region).
    // lane l: row l>>3, phys chunk l&7  <- global logical chunk (l&7)^(l>>3).
    const int srow = lane >> 3;
    const int scol = ((lane & 7) ^ srow) * 8;  // pre-swizzled source col (elems)
    const __bf16* gA = A + (size_t)(m0 + wave * 8 + srow) * DIN + scol;
    const __bf16* gB = Bw + (size_t)(n0 + wave * 8 + srow) * DIN + scol;
    const int so0 = wave * 512;        // LDS elem offset, call 0 (rows 0-63)
    const int so1 = (8 + wave) * 512;  // call 1 (rows 64-127)

#define STAGE_A(buf, kk)                                      \
    do {                                                      \
        load_lds16(gA + (kk), &lsA[buf][0][so0]);             \
        load_lds16(gA + 64 * DIN + (kk), &lsA[buf][0][so1]);  \
        load_lds16(gA + 128 * DIN + (kk), &lsA[buf][1][so0]); \
        load_lds16(gA + 192 * DIN + (kk), &lsA[buf][1][so1]); \
    } while (0)
#define STAGE_B(buf, kk)                                      \
    do {                                                      \
        load_lds16(gB + (kk), &lsB[buf][0][so0]);             \
        load_lds16(gB + 64 * DIN + (kk), &lsB[buf][0][so1]);  \
        load_lds16(gB + 128 * DIN + (kk), &lsB[buf][1][so0]); \
        load_lds16(gB + 192 * DIN + (kk), &lsB[buf][1][so1]); \
    } while (0)

    // Fragment addressing: A[m = lane&15][k = ksub*32 + (lane>>4)*8 + j].
    // phys chunk = (ksub*4 + (lane>>4)) ^ (lane&7); row offsets are mult of 16
    // so row&7 == lane&7 always.
    const int frow = lane & 15;
    const int fc0 = ((lane >> 4) ^ (lane & 7)) * 8;        // ksub=0, elems
    const int fc1 = ((4 + (lane >> 4)) ^ (lane & 7)) * 8;  // ksub=1

    f32x4 acc[8][4];
#pragma unroll
    for (int i = 0; i < 8; ++i)
#pragma unroll
        for (int j = 0; j < 4; ++j) acc[i][j] = f32x4{0.f, 0.f, 0.f, 0.f};

    // Prologue: stage tile 0 into buf 0, full drain once.
    STAGE_A(0, 0);
    STAGE_B(0, 0);
    asm volatile("s_waitcnt vmcnt(0)\n\ts_barrier" ::: "memory");

#pragma unroll 2
    for (int t = 0; t < KTILES; ++t) {
        const int cur = t & 1;
        const int kn = t * BK + BK;
        const __bf16* baseA = &lsA[cur][wm][0];
        const __bf16* baseB = &lsB[cur][wn >> 1][(wn & 1) * (64 * BK)];
#pragma unroll
        for (int ph = 0; ph < 4; ++ph) {
            const int mh = ph >> 1;  // quadrant: M half of the wave's 128 rows
            const int nh = ph & 1;   //           N half of the wave's 64 cols
            bf16x8 af[4][2], bfr[2][2];
#pragma unroll
            for (int i = 0; i < 4; ++i) {
                const int ro = ((mh * 4 + i) * 16 + frow) * BK;
                af[i][0] = *(const bf16x8*)&baseA[ro + fc0];
                af[i][1] = *(const bf16x8*)&baseA[ro + fc1];
            }
#pragma unroll
            for (int j = 0; j < 2; ++j) {
                const int ro = ((nh * 2 + j) * 16 + frow) * BK;
                bfr[j][0] = *(const bf16x8*)&baseB[ro + fc0];
                bfr[j][1] = *(const bf16x8*)&baseB[ro + fc1];
            }
            // Prefetch next K-tile into the other buffer (freed at the end of
            // tile t-1). Issued phases 0-1 -> ~3 phases of latency cover
            // before the boundary drain consumes it.
            if (t < KTILES - 1) {
                if (ph == 0) STAGE_A(cur ^ 1, kn);
                if (ph == 1) STAGE_B(cur ^ 1, kn);
            }
            // Phase barrier WITHOUT vmcnt drain: prefetch stays in flight.
            asm volatile("s_barrier" ::: "memory");
            asm volatile("s_waitcnt lgkmcnt(0)" ::: "memory");
            __builtin_amdgcn_sched_barrier(0);  // rule #18: pin MFMA below wait
            __builtin_amdgcn_s_setprio(1);
#pragma unroll
            for (int i = 0; i < 4; ++i)
#pragma unroll
                for (int j = 0; j < 2; ++j) {
                    acc[mh * 4 + i][nh * 2 + j] = __builtin_amdgcn_mfma_f32_16x16x32_bf16(
                        af[i][0], bfr[j][0], acc[mh * 4 + i][nh * 2 + j], 0, 0, 0);
                    acc[mh * 4 + i][nh * 2 + j] = __builtin_amdgcn_mfma_f32_16x16x32_bf16(
                        af[i][1], bfr[j][1], acc[mh * 4 + i][nh * 2 + j], 0, 0, 0);
                }
            __builtin_amdgcn_s_setprio(0);
            if (ph == 3) {
                // K-tile boundary: own loads done + barrier => ALL waves'
                // loads visible before next tile's ds_reads (cross-wave).
                asm volatile("s_waitcnt vmcnt(0)\n\ts_barrier" ::: "memory");
            } else {
                asm volatile("s_barrier" ::: "memory");
            }
        }
    }
#undef STAGE_A
#undef STAGE_B

    // Epilogue: C/D layout col = lane&15 (n), row = (lane>>4)*4 + reg (m).
    const int rbase = (lane >> 4) * 4;
#pragma unroll
    for (int nt = 0; nt < 4; ++nt) {
        const int n = n0 + wn * 64 + nt * 16 + frow;
        const float bv = bias[n];
#pragma unroll
        for (int mt = 0; mt < 8; ++mt) {
            const int m = m0 + wm * 128 + mt * 16 + rbase;
            float* cp = C + (size_t)m * DOUT + n;
#pragma unroll
            for (int r = 0; r < 4; ++r) cp[(size_t)r * DOUT] = acc[mt][nt][r] + bv;
        }
    }
}

// ---------------------------------------------------------------------------
extern "C" void kernel_launch(void* const* d_in, const int* in_sizes, int n_in,
                              void* d_out, int out_size, void* d_ws, size_t ws_size,
                              hipStream_t stream) {
    const float* x  = (const float*)d_in[0];
    const float* W  = (const float*)d_in[1];
    const float* b  = (const float*)d_in[2];
    const float* A1 = (const float*)d_in[3];
    const float* B1 = (const float*)d_in[4];
    const float* A2 = (const float*)d_in[5];
    const float* B2 = (const float*)d_in[6];
    float* out = (float*)d_out;

    // Workspace: [x_bf16: 64 MB][Weff_bf16: 2 MB]
    __bf16* xb   = (__bf16*)d_ws;
    __bf16* Weff = (__bf16*)((char*)d_ws + (size_t)TOKENS * DIN * sizeof(__bf16));

    cvt_x_kernel<<<TOKENS * DIN / (256 * 8), 256, 0, stream>>>(x, xb);
    weff_kernel<<<DOUT * DIN / 256, 256, 0, stream>>>(W, A1, B1, A2, B2, Weff);
    gemm_bt_kernel<<<(TOKENS / BM) * (DOUT / BN), 512, 0, stream>>>(xb, Weff, b, out);
}

// Round 2
// 326.256 us; speedup vs baseline: 1.0235x; 1.0235x over previous
//
#include <hip/hip_runtime.h>

#define TOKENS 32768
#define DIN 1024
#define DOUT 1024
#define RANK 16
#define SCALE1 0.5f
#define SCALE2 1.0f

// R7: 256x256 tile, BK=64, 8 waves. Phases = m-quarters with B-frags hoisted
// to registers once per K-tile -> 24 ds_read_b128/K-tile/wave (the minimum;
// R6's quadrant phases reloaded both operands = 48 reads -> LDS-read pipe 2x
// the MFMA pipe, MfmaUtil 25%). Same staging/swizzle/epilogue as R6 (verified
// correct).
#define BM 256
#define BN 256
#define BK 64
#define KTILES (DIN / BK)  // 16

typedef __bf16 bf16x8 __attribute__((ext_vector_type(8)));
typedef float f32x4 __attribute__((ext_vector_type(4)));

// Async global->LDS, 16B per lane. LDS dest is wave-uniform base + lane*16.
__device__ __forceinline__ void load_lds16(const void* gptr, void* lptr) {
    __builtin_amdgcn_global_load_lds(
        (__attribute__((address_space(1))) void*)gptr,
        (__attribute__((address_space(3))) void*)lptr, 16, 0, 0);
}

// ---------------------------------------------------------------------------
// Kernel 1: Weff = W + 0.5*B1@A1 + 1.0*B2@A2, cast to bf16.  [DOUT, DIN]
// ---------------------------------------------------------------------------
__global__ void weff_kernel(const float* __restrict__ W, const float* __restrict__ A1,
                            const float* __restrict__ B1, const float* __restrict__ A2,
                            const float* __restrict__ B2, __bf16* __restrict__ Weff) {
    int idx = blockIdx.x * blockDim.x + threadIdx.x;  // over DOUT*DIN
    int o = idx >> 10;
    int i = idx & 1023;
    float s1 = 0.f, s2 = 0.f;
#pragma unroll
    for (int r = 0; r < RANK; ++r) {
        s1 += B1[o * RANK + r] * A1[r * DIN + i];
        s2 += B2[o * RANK + r] * A2[r * DIN + i];
    }
    Weff[idx] = (__bf16)(W[idx] + SCALE1 * s1 + SCALE2 * s2);
}

// ---------------------------------------------------------------------------
// Kernel 2: x fp32 -> bf16, 8 elems/thread, 16B stores. Streaming-bound ~30us;
// fusing into the GEMM exposed HBM latency on the critical path (R4: 250us).
// ---------------------------------------------------------------------------
__global__ void cvt_x_kernel(const float* __restrict__ x, __bf16* __restrict__ xb) {
    int i = (blockIdx.x * blockDim.x + threadIdx.x) * 8;
    float4 a = *(const float4*)(x + i);
    float4 b = *(const float4*)(x + i + 4);
    bf16x8 v;
    v[0] = (__bf16)a.x; v[1] = (__bf16)a.y; v[2] = (__bf16)a.z; v[3] = (__bf16)a.w;
    v[4] = (__bf16)b.x; v[5] = (__bf16)b.y; v[6] = (__bf16)b.z; v[7] = (__bf16)b.w;
    *(bf16x8*)(xb + i) = v;
}

// ---------------------------------------------------------------------------
// Kernel 3: out[M,N] = A[M,K] @ Bw[N,K]^T + bias.  256x256 tile, 4 m-phases.
//
// LDS layout per half-tile (128 rows x 64 bf16): row-major, 8 chunks of 16B
// per row, phys_chunk = logical_chunk ^ (row & 7). global_load_lds writes
// linearly (lane l -> row l>>3, phys chunk l&7 of a 1024B slab), so the
// inverse swizzle is applied to the per-lane GLOBAL source address and the
// same XOR on the ds_read side (both-sides-or-neither rule).
// ds_read_b128 frag pattern: row ≡ lane&15 (mod 16), chunk = ksub*4+(lane>>4)
// -> phys = chunk ^ (lane&7): conflict-free (0 conflicts measured in R6).
//
// Phase plan per K-tile (per wave, output 128x64):
//   ph0: ds_read B all 8 frags -> regs (held all tile) + A[q0] 4; STAGE_A(t+1)
//   ph1: ds_read A[q1] 4;                                        STAGE_B(t+1)
//   ph2: ds_read A[q2] 4
//   ph3: ds_read A[q3] 4; tile-end vmcnt(0) drain
// Each phase: barrier -> lgkmcnt(0) -> sched_barrier -> setprio(1) -> 16 MFMA.
// 24 reads/K-tile/wave = LDS-read ~2300cy/CU/K-tile ~= MFMA 2150cy (co-crit).
// ---------------------------------------------------------------------------
__global__ __launch_bounds__(512, 2) void gemm_bt_kernel(
    const __bf16* __restrict__ A,   // [TOKENS, DIN] bf16
    const __bf16* __restrict__ Bw,  // [DOUT, DIN] bf16
    const float* __restrict__ bias, float* __restrict__ C) {
    __shared__ alignas(16) __bf16 lsA[2][2][128 * BK];  // [buf][half] 2x2x16KB
    __shared__ alignas(16) __bf16 lsB[2][2][128 * BK];  // total 128 KiB

    const int tid = threadIdx.x;
    const int wave = tid >> 6;
    const int lane = tid & 63;

    // XCD-aware swizzle: 512 blocks = 8 xcds x 64 (bijective). Within an xcd:
    // 16 m-tiles x 4 n-tiles, n fastest, so the 4 blocks sharing an x m-tile
    // are temporally adjacent on ONE xcd and Weff (2MB) stays L2-resident.
    const int l = blockIdx.x;
    const int xcd = l & 7;
    const int s = l >> 3;
    const int m0 = (xcd * 16 + (s >> 2)) * BM;
    const int n0 = (s & 3) * BN;

    const int wm = wave >> 2;  // 0..1  (M half: 128 rows)
    const int wn = wave & 3;   // 0..3  (N quarter: 64 cols)

    // Staging: per call a wave fills one 1024B slab (8 rows x 64 cols region).
    // lane l: row l>>3, phys chunk l&7  <- global logical chunk (l&7)^(l>>3).
    const int srow = lane >> 3;
    const int scol = ((lane & 7) ^ srow) * 8;  // pre-swizzled source col (elems)
    const __bf16* gA = A + (size_t)(m0 + wave * 8 + srow) * DIN + scol;
    const __bf16* gB = Bw + (size_t)(n0 + wave * 8 + srow) * DIN + scol;
    const int so0 = wave * 512;        // LDS elem offset, call 0 (rows 0-63)
    const int so1 = (8 + wave) * 512;  // call 1 (rows 64-127)

#define STAGE_A(buf, kk)                                      \
    do {                                                      \
        load_lds16(gA + (kk), &lsA[buf][0][so0]);             \
        load_lds16(gA + 64 * DIN + (kk), &lsA[buf][0][so1]);  \
        load_lds16(gA + 128 * DIN + (kk), &lsA[buf][1][so0]); \
        load_lds16(gA + 192 * DIN + (kk), &lsA[buf][1][so1]); \
    } while (0)
#define STAGE_B(buf, kk)                                      \
    do {                                                      \
        load_lds16(gB + (kk), &lsB[buf][0][so0]);             \
        load_lds16(gB + 64 * DIN + (kk), &lsB[buf][0][so1]);  \
        load_lds16(gB + 128 * DIN + (kk), &lsB[buf][1][so0]); \
        load_lds16(gB + 192 * DIN + (kk), &lsB[buf][1][so1]); \
    } while (0)

    // Fragment addressing: operand[row ≡ lane&15 (mod 16)][k = ksub*32 +
    // (lane>>4)*8 + j].  phys chunk = (ksub*4 + (lane>>4)) ^ (lane&7); row
    // offsets are multiples of 16 so row&7 == lane&7 always.
    const int frow = lane & 15;
    const int fc0 = ((lane >> 4) ^ (lane & 7)) * 8;        // ksub=0, elems
    const int fc1 = ((4 + (lane >> 4)) ^ (lane & 7)) * 8;  // ksub=1

    f32x4 acc[8][4];
#pragma unroll
    for (int i = 0; i < 8; ++i)
#pragma unroll
        for (int j = 0; j < 4; ++j) acc[i][j] = f32x4{0.f, 0.f, 0.f, 0.f};

    // Prologue: stage tile 0 into buf 0, full drain once.
    STAGE_A(0, 0);
    STAGE_B(0, 0);
    asm volatile("s_waitcnt vmcnt(0)\n\ts_barrier" ::: "memory");

#pragma unroll 2
    for (int t = 0; t < KTILES; ++t) {
        const int cur = t & 1;
        const int kn = t * BK + BK;
        const __bf16* baseA = &lsA[cur][wm][0];
        const __bf16* baseB = &lsB[cur][wn >> 1][(wn & 1) * (64 * BK)];
        bf16x8 bfr[4][2];  // all 4 n-frags x 2 ksub, live across the K-tile
#pragma unroll
        for (int ph = 0; ph < 4; ++ph) {
            if (ph == 0) {
#pragma unroll
                for (int j = 0; j < 4; ++j) {
                    const int ro = (j * 16 + frow) * BK;
                    bfr[j][0] = *(const bf16x8*)&baseB[ro + fc0];
                    bfr[j][1] = *(const bf16x8*)&baseB[ro + fc1];
                }
            }
            bf16x8 af[2][2];
#pragma unroll
            for (int i = 0; i < 2; ++i) {
                const int ro = ((ph * 2 + i) * 16 + frow) * BK;
                af[i][0] = *(const bf16x8*)&baseA[ro + fc0];
                af[i][1] = *(const bf16x8*)&baseA[ro + fc1];
            }
            // Prefetch next K-tile into the freed buffer; loads stay in
            // flight across the phase barriers (no vmcnt here).
            if (t < KTILES - 1) {
                if (ph == 0) STAGE_A(cur ^ 1, kn);
                if (ph == 1) STAGE_B(cur ^ 1, kn);
            }
            asm volatile("s_barrier" ::: "memory");
            asm volatile("s_waitcnt lgkmcnt(0)" ::: "memory");
            __builtin_amdgcn_sched_barrier(0);  // rule #18: pin MFMA below wait
            __builtin_amdgcn_s_setprio(1);
#pragma unroll
            for (int i = 0; i < 2; ++i)
#pragma unroll
                for (int j = 0; j < 4; ++j) {
                    acc[ph * 2 + i][j] = __builtin_amdgcn_mfma_f32_16x16x32_bf16(
                        af[i][0], bfr[j][0], acc[ph * 2 + i][j], 0, 0, 0);
                    acc[ph * 2 + i][j] = __builtin_amdgcn_mfma_f32_16x16x32_bf16(
                        af[i][1], bfr[j][1], acc[ph * 2 + i][j], 0, 0, 0);
                }
            __builtin_amdgcn_s_setprio(0);
            if (ph == 3) {
                // K-tile boundary: own prefetch done + barrier => all waves'
                // staged data visible before next tile's ds_reads.
                asm volatile("s_waitcnt vmcnt(0)\n\ts_barrier" ::: "memory");
            } else {
                asm volatile("s_barrier" ::: "memory");
            }
        }
    }
#undef STAGE_A
#undef STAGE_B

    // Epilogue: C/D layout col = lane&15 (n), row = (lane>>4)*4 + reg (m).
    const int rbase = (lane >> 4) * 4;
#pragma unroll
    for (int nt = 0; nt < 4; ++nt) {
        const int n = n0 + wn * 64 + nt * 16 + frow;
        const float bv = bias[n];
#pragma unroll
        for (int mt = 0; mt < 8; ++mt) {
            const int m = m0 + wm * 128 + mt * 16 + rbase;
            float* cp = C + (size_t)m * DOUT + n;
#pragma unroll
            for (int r = 0; r < 4; ++r) cp[(size_t)r * DOUT] = acc[mt][nt][r] + bv;
        }
    }
}

// ---------------------------------------------------------------------------
extern "C" void kernel_launch(void* const* d_in, const int* in_sizes, int n_in,
                              void* d_out, int out_size, void* d_ws, size_t ws_size,
                              hipStream_t stream) {
    const float* x  = (const float*)d_in[0];
    const float* W  = (const float*)d_in[1];
    const float* b  = (const float*)d_in[2];
    const float* A1 = (const float*)d_in[3];
    const float* B1 = (const float*)d_in[4];
    const float* A2 = (const float*)d_in[5];
    const float* B2 = (const float*)d_in[6];
    float* out = (float*)d_out;

    // Workspace: [x_bf16: 64 MB][Weff_bf16: 2 MB]
    __bf16* xb   = (__bf16*)d_ws;
    __bf16* Weff = (__bf16*)((char*)d_ws + (size_t)TOKENS * DIN * sizeof(__bf16));

    cvt_x_kernel<<<TOKENS * DIN / (256 * 8), 256, 0, stream>>>(x, xb);
    weff_kernel<<<DOUT * DIN / 256, 256, 0, stream>>>(W, A1, B1, A2, B2, Weff);
    gemm_bt_kernel<<<(TOKENS / BM) * (DOUT / BN), 512, 0, stream>>>(xb, Weff, b, out);
}

// Round 3
// 325.842 us; speedup vs baseline: 1.0248x; 1.0013x over previous
//
#include <hip/hip_runtime.h>

#define TOKENS 32768
#define DIN 1024
#define DOUT 1024
#define RANK 16
#define SCALE1 0.5f
#define SCALE2 1.0f

// R8: 256x256 tile, BK=64, 8 waves, 2 phases/K-tile (k-halves), COUNTED vmcnt.
// Staging is restructured into k-half slabs (A_k0,A_k1,B_k0,B_k1, each 256x32)
// so phase ph(t,ksub) depends only on the wave's OLDEST 4 loads -> the tile
// boundary drain vmcnt(0) (R7's bottleneck, T4 violation) becomes vmcnt(4).
// Steady state: 8 loads in flight/wave, waited ~1.7 phases (~1700cy) after
// issue vs ~900cy HBM latency. Barriers 8->2 per K-tile. Per-slab layout ==
// R5's proven BK=32 tile (swizzle verified 0 conflicts).
#define BM 256
#define BN 256
#define BK 64
#define KTILES (DIN / BK)  // 16

typedef __bf16 bf16x8 __attribute__((ext_vector_type(8)));
typedef float f32x4 __attribute__((ext_vector_type(4)));

// Async global->LDS, 16B per lane. LDS dest is wave-uniform base + lane*16.
__device__ __forceinline__ void load_lds16(const void* gptr, void* lptr) {
    __builtin_amdgcn_global_load_lds(
        (__attribute__((address_space(1))) void*)gptr,
        (__attribute__((address_space(3))) void*)lptr, 16, 0, 0);
}

// ---------------------------------------------------------------------------
// Kernel 1: Weff = W + 0.5*B1@A1 + 1.0*B2@A2, cast to bf16.  [DOUT, DIN]
// ---------------------------------------------------------------------------
__global__ void weff_kernel(const float* __restrict__ W, const float* __restrict__ A1,
                            const float* __restrict__ B1, const float* __restrict__ A2,
                            const float* __restrict__ B2, __bf16* __restrict__ Weff) {
    int idx = blockIdx.x * blockDim.x + threadIdx.x;  // over DOUT*DIN
    int o = idx >> 10;
    int i = idx & 1023;
    float s1 = 0.f, s2 = 0.f;
#pragma unroll
    for (int r = 0; r < RANK; ++r) {
        s1 += B1[o * RANK + r] * A1[r * DIN + i];
        s2 += B2[o * RANK + r] * A2[r * DIN + i];
    }
    Weff[idx] = (__bf16)(W[idx] + SCALE1 * s1 + SCALE2 * s2);
}

// ---------------------------------------------------------------------------
// Kernel 2: x fp32 -> bf16, 8 elems/thread, 16B stores. Streaming-bound ~30us;
// fusing into the GEMM exposed HBM latency on the critical path (R4: 250us).
// ---------------------------------------------------------------------------
__global__ void cvt_x_kernel(const float* __restrict__ x, __bf16* __restrict__ xb) {
    int i = (blockIdx.x * blockDim.x + threadIdx.x) * 8;
    float4 a = *(const float4*)(x + i);
    float4 b = *(const float4*)(x + i + 4);
    bf16x8 v;
    v[0] = (__bf16)a.x; v[1] = (__bf16)a.y; v[2] = (__bf16)a.z; v[3] = (__bf16)a.w;
    v[4] = (__bf16)b.x; v[5] = (__bf16)b.y; v[6] = (__bf16)b.z; v[7] = (__bf16)b.w;
    *(bf16x8*)(xb + i) = v;
}

// ---------------------------------------------------------------------------
// Kernel 3: out[M,N] = A[M,K] @ Bw[N,K]^T + bias.  256x256 tile.
//
// LDS: per K-tile 4 slabs of 256 rows x 32 cols bf16 (16KB each), double-
// buffered: lsA[buf][ksub], lsB[buf][ksub].  Slab layout (== R5's verified
// BK=32 tile): row-major, 4 chunks of 16B per row, phys_chunk = chunk ^
// ((row>>1)&3).  global_load_lds writes linearly (lane l -> row l>>2, phys
// chunk l&3 of a 1KB 16-row stripe), so the inverse swizzle goes on the
// per-lane GLOBAL source column: logical chunk (l&3) ^ ((l>>3)&3).
// Frag reads (row = msub*16 + (lane&15), chunk = lane>>4): phys chunk =
// (lane>>4) ^ ((lane>>1)&3) -> 2-way max bank aliasing = free (R5: 0
// conflicts measured).
//
// Per-wave issue/wait stream (steady state):
//   ph(t,0): ds_read slab(t,k0) x12 | issue STAGE(t+1,k0) x4 | lgkm0 |
//            32 MFMA | vmcnt(4)  [waits (t,k1), leaves (t+1,k0)] | barrier
//   ph(t,1): ds_read slab(t,k1) x12 | issue STAGE(t+1,k1) x4 | lgkm0 |
//            32 MFMA | vmcnt(4)  [waits (t+1,k0), leaves (t+1,k1)] | barrier
// Prologue: STAGE(0,k0) STAGE(0,k1), vmcnt(4), barrier.  Tail (t=15):
// ph0 ends vmcnt(0); ph1 ends with nothing (fall into epilogue).
// ---------------------------------------------------------------------------
__global__ __launch_bounds__(512, 2) void gemm_bt_kernel(
    const __bf16* __restrict__ A,   // [TOKENS, DIN] bf16
    const __bf16* __restrict__ Bw,  // [DOUT, DIN] bf16
    const float* __restrict__ bias, float* __restrict__ C) {
    __shared__ alignas(16) __bf16 lsA[2][2][256 * 32];  // [buf][ksub] 16KB each
    __shared__ alignas(16) __bf16 lsB[2][2][256 * 32];  // total 128 KiB

    const int tid = threadIdx.x;
    const int wave = tid >> 6;
    const int lane = tid & 63;

    // XCD-aware swizzle: 512 blocks = 8 xcds x 64 (bijective). Within an xcd:
    // 16 m-tiles x 4 n-tiles, n fastest, so the 4 blocks sharing an A m-tile
    // are temporally adjacent on ONE xcd and Weff (2MB) stays L2-resident.
    const int l = blockIdx.x;
    const int xcd = l & 7;
    const int s = l >> 3;
    const int m0 = (xcd * 16 + (s >> 2)) * BM;
    const int n0 = (s & 3) * BN;

    const int wm = wave >> 2;  // 0..1  (M half: 128 rows)
    const int wn = wave & 3;   // 0..3  (N quarter: 64 cols)

    // Staging: one call = one wave = 16 rows x 32 cols (1KB stripe).
    // lane l: row l>>2 (within 16), phys chunk l&3 <- logical (l&3)^((l>>3)&3).
    const int srow = lane >> 2;
    const int scol = ((lane & 3) ^ ((lane >> 3) & 3)) * 8;  // source col (elems)
    const __bf16* gA = A + (size_t)(m0 + wave * 16 + srow) * DIN + scol;
    const __bf16* gB = Bw + (size_t)(n0 + wave * 16 + srow) * DIN + scol;
    const int sdst = wave * 16 * 32;  // LDS elem offset of this wave's stripe

    // Per call c (0/1): rows c*128 + wave*16 + (0..15).
#define STAGE(buf, ks, kk)                                               \
    do {                                                                 \
        load_lds16(gA + (kk), &lsA[buf][ks][sdst]);                      \
        load_lds16(gA + 128 * DIN + (kk), &lsA[buf][ks][sdst + 4096]);   \
        load_lds16(gB + (kk), &lsB[buf][ks][sdst]);                      \
        load_lds16(gB + 128 * DIN + (kk), &lsB[buf][ks][sdst + 4096]);   \
    } while (0)

    // Fragment addressing within a slab: row = sub*16 + frow, chunk = lane>>4,
    // phys chunk = (lane>>4) ^ ((lane>>1)&3)  (row offsets are mult of 16 and
    // wm*128 / wn*64 are mult of 4 rows, so (row>>1)&3 == ((lane&15)>>1)&3).
    const int frow = lane & 15;
    const int fsw = (((lane >> 4) ^ ((lane >> 1) & 3))) * 8;  // elem offset

    f32x4 acc[8][4];
#pragma unroll
    for (int i = 0; i < 8; ++i)
#pragma unroll
        for (int j = 0; j < 4; ++j) acc[i][j] = f32x4{0.f, 0.f, 0.f, 0.f};

    // Prologue: stage tile 0 (both k-slabs) into buf 0; wait only k0.
    STAGE(0, 0, 0);
    STAGE(0, 1, 32);
    asm volatile("s_waitcnt vmcnt(4)\n\ts_barrier" ::: "memory");

#pragma unroll 2
    for (int t = 0; t < KTILES; ++t) {
        const int cur = t & 1;
#pragma unroll
        for (int ksub = 0; ksub < 2; ++ksub) {
            const __bf16* bA = &lsA[cur][ksub][wm * 128 * 32];
            const __bf16* bB = &lsB[cur][ksub][wn * 64 * 32];
            bf16x8 af[8], bf[4];
#pragma unroll
            for (int i = 0; i < 8; ++i)
                af[i] = *(const bf16x8*)&bA[(i * 16 + frow) * 32 + fsw];
#pragma unroll
            for (int j = 0; j < 4; ++j)
                bf[j] = *(const bf16x8*)&bB[(j * 16 + frow) * 32 + fsw];

            // Prefetch slab (t+1, ksub) into the other buffer. Its LDS region
            // was last read at ph(t-1,ksub), 2 barriers ago -> WAR-safe.
            if (t < KTILES - 1) STAGE(cur ^ 1, ksub, (t + 1) * 64 + ksub * 32);

            asm volatile("s_waitcnt lgkmcnt(0)" ::: "memory");
            __builtin_amdgcn_sched_barrier(0);  // rule #18: pin MFMA below wait
            __builtin_amdgcn_s_setprio(1);
#pragma unroll
            for (int i = 0; i < 8; ++i)
#pragma unroll
                for (int j = 0; j < 4; ++j)
                    acc[i][j] = __builtin_amdgcn_mfma_f32_16x16x32_bf16(
                        af[i], bf[j], acc[i][j], 0, 0, 0);
            __builtin_amdgcn_s_setprio(0);

            // End-of-phase: guarantee next phase's slab, keep the rest in
            // flight. Never vmcnt(0) until the final tile.
            if (t < KTILES - 1) {
                asm volatile("s_waitcnt vmcnt(4)\n\ts_barrier" ::: "memory");
            } else if (ksub == 0) {
                asm volatile("s_waitcnt vmcnt(0)\n\ts_barrier" ::: "memory");
            }
            // (t=15, ksub=1): no wait, no barrier -> epilogue.
        }
    }
#undef STAGE

    // Epilogue: C/D layout col = lane&15 (n), row = (lane>>4)*4 + reg (m).
    const int rbase = (lane >> 4) * 4;
#pragma unroll
    for (int nt = 0; nt < 4; ++nt) {
        const int n = n0 + wn * 64 + nt * 16 + frow;
        const float bv = bias[n];
#pragma unroll
        for (int mt = 0; mt < 8; ++mt) {
            const int m = m0 + wm * 128 + mt * 16 + rbase;
            float* cp = C + (size_t)m * DOUT + n;
#pragma unroll
            for (int r = 0; r < 4; ++r) cp[(size_t)r * DOUT] = acc[mt][nt][r] + bv;
        }
    }
}

// ---------------------------------------------------------------------------
extern "C" void kernel_launch(void* const* d_in, const int* in_sizes, int n_in,
                              void* d_out, int out_size, void* d_ws, size_t ws_size,
                              hipStream_t stream) {
    const float* x  = (const float*)d_in[0];
    const float* W  = (const float*)d_in[1];
    const float* b  = (const float*)d_in[2];
    const float* A1 = (const float*)d_in[3];
    const float* B1 = (const float*)d_in[4];
    const float* A2 = (const float*)d_in[5];
    const float* B2 = (const float*)d_in[6];
    float* out = (float*)d_out;

    // Workspace: [x_bf16: 64 MB][Weff_bf16: 2 MB]
    __bf16* xb   = (__bf16*)d_ws;
    __bf16* Weff = (__bf16*)((char*)d_ws + (size_t)TOKENS * DIN * sizeof(__bf16));

    cvt_x_kernel<<<TOKENS * DIN / (256 * 8), 256, 0, stream>>>(x, xb);
    weff_kernel<<<DOUT * DIN / 256, 256, 0, stream>>>(W, A1, B1, A2, B2, Weff);
    gemm_bt_kernel<<<(TOKENS / BM) * (DOUT / BN), 512, 0, stream>>>(xb, Weff, b, out);
}

// Round 5
// 321.137 us; speedup vs baseline: 1.0398x; 1.0147x over previous
//
#include <hip/hip_runtime.h>

#define TOKENS 32768
#define DIN 1024
#define DOUT 1024
#define RANK 16
#define SCALE1 0.5f
#define SCALE2 1.0f

// R10: R9's 8-phase counted-vmcnt schedule with the WAR race fixed by
// QUARTER-granularity staging (1 gload = 64 rows = exactly one region that
// frees at a known phase). R9 staged 128-row halves into the live buffer at
// ph1, overwriting rows 64..127 still read at ph2 -> absmax 6.875.
// Free schedule: A q0,q2 free after ph0 -> stage@ph1; B q0..q3 free after
// ph1 -> stage@ph2; A q1,q3 free after ph2 -> stage@ph3. One vmcnt(8)/tile.
#define BM 256
#define BN 256
#define BK 64
#define KTILES (DIN / BK)  // 16

typedef __bf16 bf16x8 __attribute__((ext_vector_type(8)));
typedef float f32x4 __attribute__((ext_vector_type(4)));

// Async global->LDS, 16B per lane. LDS dest is wave-uniform base + lane*16.
__device__ __forceinline__ void load_lds16(const void* gptr, void* lptr) {
    __builtin_amdgcn_global_load_lds(
        (__attribute__((address_space(1))) void*)gptr,
        (__attribute__((address_space(3))) void*)lptr, 16, 0, 0);
}

// ---------------------------------------------------------------------------
// Kernel 1: Weff = W + 0.5*B1@A1 + 1.0*B2@A2, cast to bf16.  [DOUT, DIN]
// ---------------------------------------------------------------------------
__global__ void weff_kernel(const float* __restrict__ W, const float* __restrict__ A1,
                            const float* __restrict__ B1, const float* __restrict__ A2,
                            const float* __restrict__ B2, __bf16* __restrict__ Weff) {
    int idx = blockIdx.x * blockDim.x + threadIdx.x;  // over DOUT*DIN
    int o = idx >> 10;
    int i = idx & 1023;
    float s1 = 0.f, s2 = 0.f;
#pragma unroll
    for (int r = 0; r < RANK; ++r) {
        s1 += B1[o * RANK + r] * A1[r * DIN + i];
        s2 += B2[o * RANK + r] * A2[r * DIN + i];
    }
    Weff[idx] = (__bf16)(W[idx] + SCALE1 * s1 + SCALE2 * s2);
}

// ---------------------------------------------------------------------------
// Kernel 2: x fp32 -> bf16, 8 elems/thread, 16B stores. Streaming-bound ~30us;
// fusing into the GEMM exposed HBM latency on the critical path (R4: 250us).
// ---------------------------------------------------------------------------
__global__ void cvt_x_kernel(const float* __restrict__ x, __bf16* __restrict__ xb) {
    int i = (blockIdx.x * blockDim.x + threadIdx.x) * 8;
    float4 a = *(const float4*)(x + i);
    float4 b = *(const float4*)(x + i + 4);
    bf16x8 v;
    v[0] = (__bf16)a.x; v[1] = (__bf16)a.y; v[2] = (__bf16)a.z; v[3] = (__bf16)a.w;
    v[4] = (__bf16)b.x; v[5] = (__bf16)b.y; v[6] = (__bf16)b.z; v[7] = (__bf16)b.w;
    *(bf16x8*)(xb + i) = v;
}

// ---------------------------------------------------------------------------
// Kernel 3: out[M,N] = A[M,K] @ Bw[N,K]^T + bias.  256x256, BK=64, 8 waves.
//
// LDS half (128 rows x 64 bf16), quarters = 64-row sub-blocks. Row-major, 8
// chunks of 16B/row, phys_chunk = chunk ^ (row&7). gload_lds writes linearly
// (lane l -> row l>>3, phys chunk l&7 of its wave's 8-row slab), inverse
// swizzle on the per-lane GLOBAL source col; same XOR on ds_read side.
// Frag reads: phys chunk = (ksub*4 + lane>>4) ^ (lane&7): 0 conflicts
// (measured R6-R8).
//
// Snake phases per tile t (cur=t&1), B-frags held all tile:
//   ph0 (Alo,Blo): read A-lo(8)+B-lo(4);                     16 MFMA [0..3][0..1]
//   ph1 (Alo,Bhi): read B-hi(4); stage A q0,q2 (t+2,cur);    16 MFMA [0..3][2..3]
//   ph2 (Ahi,Bhi): read A-hi(8); stage B q0..q3 (t+2,cur);   16 MFMA [4..7][2..3]
//   ph3 (Ahi,Blo): no reads;     stage A q1,q3 (t+2,cur);    16 MFMA [4..7][0..1]
// Each phase: [reads|stages] BAR lgkm0 SCHED setprio1 MFMA setprio0 BAR.
// ph3's closing wait: vmcnt(8) (drains tile t+1's 8, leaves t+2's 8).
// WAR proof: each staged quarter's last ds_read is >=1 closed phase earlier
// (all waves lgkm0'd before that phase's end barrier).
// Ledger: enter t with t+1's 8 outstanding; +8 during t; vmcnt(8) at end.
// Prologue: tile0(8)+tile1(8), vmcnt(8). Tail: t=14 vmcnt(0), t=15 bare.
// ---------------------------------------------------------------------------
__global__ __launch_bounds__(512, 2) void gemm_bt_kernel(
    const __bf16* __restrict__ A,   // [TOKENS, DIN] bf16
    const __bf16* __restrict__ Bw,  // [DOUT, DIN] bf16
    const float* __restrict__ bias, float* __restrict__ C) {
    __shared__ alignas(16) __bf16 lsA[2][2][128 * BK];  // [buf][half] 2x2x16KB
    __shared__ alignas(16) __bf16 lsB[2][2][128 * BK];  // total 128 KiB

    const int tid = threadIdx.x;
    const int wave = tid >> 6;
    const int lane = tid & 63;

    // XCD-aware swizzle: 512 blocks = 8 xcds x 64 (bijective). Within an xcd:
    // 16 m-tiles x 4 n-tiles, n fastest -> Weff (2MB) L2-resident per xcd.
    const int l = blockIdx.x;
    const int xcd = l & 7;
    const int s = l >> 3;
    const int m0 = (xcd * 16 + (s >> 2)) * BM;
    const int n0 = (s & 3) * BN;

    const int wm = wave >> 2;  // 0..1  (M half: 128 rows)
    const int wn = wave & 3;   // 0..3  (N quarter: 64 cols)

    // Staging: one call = one wave = one 8-row x 64-col slab (1KB) of a
    // quarter. lane l: row l>>3, phys chunk l&7 <- logical (l&7)^(l>>3).
    const int srow = lane >> 3;
    const int scol = ((lane & 7) ^ srow) * 8;  // pre-swizzled source col
    const __bf16* gA = A + (size_t)(m0 + wave * 8 + srow) * DIN + scol;
    const __bf16* gB = Bw + (size_t)(n0 + wave * 8 + srow) * DIN + scol;
    const int sdst = wave * 512;  // elem offset of wave's slab within quarter

    // Quarter q (global rows q*64..q*64+63) = half q>>1, local rows (q&1)*64+.
#define STG_A_Q(buf, q, kk) \
    load_lds16(gA + (size_t)(q) * 64 * DIN + (kk), &lsA[buf][(q) >> 1][((q) & 1) * 4096 + sdst])
#define STG_B_Q(buf, q, kk) \
    load_lds16(gB + (size_t)(q) * 64 * DIN + (kk), &lsB[buf][(q) >> 1][((q) & 1) * 4096 + sdst])

    // Fragment addressing: row ≡ lane&15 (mod 16); phys chunk =
    // (ksub*4 + lane>>4) ^ (lane&7). Row offsets mult of 16 -> row&7==lane&7.
    const int frow = lane & 15;
    const int fc0 = ((lane >> 4) ^ (lane & 7)) * 8;        // ksub=0
    const int fc1 = ((4 + (lane >> 4)) ^ (lane & 7)) * 8;  // ksub=1

    f32x4 acc[8][4];
#pragma unroll
    for (int i = 0; i < 8; ++i)
#pragma unroll
        for (int j = 0; j < 4; ++j) acc[i][j] = f32x4{0.f, 0.f, 0.f, 0.f};

    // Prologue: tile0 -> buf0 (8 loads), tile1 -> buf1 (8 loads), wait tile0.
#pragma unroll
    for (int q = 0; q < 4; ++q) { STG_A_Q(0, q, 0); STG_B_Q(0, q, 0); }
#pragma unroll
    for (int q = 0; q < 4; ++q) { STG_A_Q(1, q, BK); STG_B_Q(1, q, BK); }
    asm volatile("s_waitcnt vmcnt(8)\n\ts_barrier" ::: "memory");

#pragma unroll 2
    for (int t = 0; t < KTILES; ++t) {
        const int cur = t & 1;
        const int kn2 = (t + 2) * BK;
        const __bf16* baseA = &lsA[cur][wm][0];
        const __bf16* baseB = &lsB[cur][wn >> 1][(wn & 1) * (64 * BK)];
        bf16x8 af[4][2], bf[4][2];

        // -------- ph0: (A-lo, B-lo); no staging --------
#pragma unroll
        for (int i = 0; i < 4; ++i) {
            const int ro = (i * 16 + frow) * BK;
            af[i][0] = *(const bf16x8*)&baseA[ro + fc0];
            af[i][1] = *(const bf16x8*)&baseA[ro + fc1];
        }
#pragma unroll
        for (int j = 0; j < 2; ++j) {
            const int ro = (j * 16 + frow) * BK;
            bf[j][0] = *(const bf16x8*)&baseB[ro + fc0];
            bf[j][1] = *(const bf16x8*)&baseB[ro + fc1];
        }
        asm volatile("s_waitcnt lgkmcnt(8)" ::: "memory");
        asm volatile("s_barrier" ::: "memory");
        asm volatile("s_waitcnt lgkmcnt(0)" ::: "memory");
        __builtin_amdgcn_sched_barrier(0);
        __builtin_amdgcn_s_setprio(1);
#pragma unroll
        for (int i = 0; i < 4; ++i)
#pragma unroll
            for (int j = 0; j < 2; ++j) {
                acc[i][j] = __builtin_amdgcn_mfma_f32_16x16x32_bf16(
                    af[i][0], bf[j][0], acc[i][j], 0, 0, 0);
                acc[i][j] = __builtin_amdgcn_mfma_f32_16x16x32_bf16(
                    af[i][1], bf[j][1], acc[i][j], 0, 0, 0);
            }
        __builtin_amdgcn_s_setprio(0);
        asm volatile("s_barrier" ::: "memory");

        // -------- ph1: (A-lo, B-hi); stage A q0,q2 of t+2 (freed @ph0) -----
#pragma unroll
        for (int j = 2; j < 4; ++j) {
            const int ro = (j * 16 + frow) * BK;
            bf[j][0] = *(const bf16x8*)&baseB[ro + fc0];
            bf[j][1] = *(const bf16x8*)&baseB[ro + fc1];
        }
        if (t + 2 < KTILES) { STG_A_Q(cur, 0, kn2); STG_A_Q(cur, 2, kn2); }
        asm volatile("s_barrier" ::: "memory");
        asm volatile("s_waitcnt lgkmcnt(0)" ::: "memory");
        __builtin_amdgcn_sched_barrier(0);
        __builtin_amdgcn_s_setprio(1);
#pragma unroll
        for (int i = 0; i < 4; ++i)
#pragma unroll
            for (int j = 2; j < 4; ++j) {
                acc[i][j] = __builtin_amdgcn_mfma_f32_16x16x32_bf16(
                    af[i][0], bf[j][0], acc[i][j], 0, 0, 0);
                acc[i][j] = __builtin_amdgcn_mfma_f32_16x16x32_bf16(
                    af[i][1], bf[j][1], acc[i][j], 0, 0, 0);
            }
        __builtin_amdgcn_s_setprio(0);
        asm volatile("s_barrier" ::: "memory");

        // -------- ph2: (A-hi, B-hi); stage B q0..q3 of t+2 (freed @ph1) ----
#pragma unroll
        for (int i = 0; i < 4; ++i) {
            const int ro = ((4 + i) * 16 + frow) * BK;
            af[i][0] = *(const bf16x8*)&baseA[ro + fc0];
            af[i][1] = *(const bf16x8*)&baseA[ro + fc1];
        }
        if (t + 2 < KTILES) {
            STG_B_Q(cur, 0, kn2); STG_B_Q(cur, 1, kn2);
            STG_B_Q(cur, 2, kn2); STG_B_Q(cur, 3, kn2);
        }
        asm volatile("s_barrier" ::: "memory");
        asm volatile("s_waitcnt lgkmcnt(0)" ::: "memory");
        __builtin_amdgcn_sched_barrier(0);
        __builtin_amdgcn_s_setprio(1);
#pragma unroll
        for (int i = 0; i < 4; ++i)
#pragma unroll
            for (int j = 2; j < 4; ++j) {
                acc[4 + i][j] = __builtin_amdgcn_mfma_f32_16x16x32_bf16(
                    af[i][0], bf[j][0], acc[4 + i][j], 0, 0, 0);
                acc[4 + i][j] = __builtin_amdgcn_mfma_f32_16x16x32_bf16(
                    af[i][1], bf[j][1], acc[4 + i][j], 0, 0, 0);
            }
        __builtin_amdgcn_s_setprio(0);
        asm volatile("s_barrier" ::: "memory");

        // -------- ph3: (A-hi, B-lo); stage A q1,q3 of t+2 (freed @ph2) -----
        if (t + 2 < KTILES) { STG_A_Q(cur, 1, kn2); STG_A_Q(cur, 3, kn2); }
        asm volatile("s_barrier" ::: "memory");
        __builtin_amdgcn_s_setprio(1);
#pragma unroll
        for (int i = 0; i < 4; ++i)
#pragma unroll
            for (int j = 0; j < 2; ++j) {
                acc[4 + i][j] = __builtin_amdgcn_mfma_f32_16x16x32_bf16(
                    af[i][0], bf[j][0], acc[4 + i][j], 0, 0, 0);
                acc[4 + i][j] = __builtin_amdgcn_mfma_f32_16x16x32_bf16(
                    af[i][1], bf[j][1], acc[4 + i][j], 0, 0, 0);
            }
        __builtin_amdgcn_s_setprio(0);
        if (t < KTILES - 2) {
            asm volatile("s_waitcnt vmcnt(8)\n\ts_barrier" ::: "memory");
        } else if (t == KTILES - 2) {
            asm volatile("s_waitcnt vmcnt(0)\n\ts_barrier" ::: "memory");
        }
        // t == KTILES-1: fall through to epilogue.
    }
#undef STG_A_Q
#undef STG_B_Q

    // Epilogue: C/D layout col = lane&15 (n), row = (lane>>4)*4 + reg (m).
    const int rbase = (lane >> 4) * 4;
#pragma unroll
    for (int nt = 0; nt < 4; ++nt) {
        const int n = n0 + wn * 64 + nt * 16 + frow;
        const float bv = bias[n];
#pragma unroll
        for (int mt = 0; mt < 8; ++mt) {
            const int m = m0 + wm * 128 + mt * 16 + rbase;
            float* cp = C + (size_t)m * DOUT + n;
#pragma unroll
            for (int r = 0; r < 4; ++r) cp[(size_t)r * DOUT] = acc[mt][nt][r] + bv;
        }
    }
}

// ---------------------------------------------------------------------------
extern "C" void kernel_launch(void* const* d_in, const int* in_sizes, int n_in,
                              void* d_out, int out_size, void* d_ws, size_t ws_size,
                              hipStream_t stream) {
    const float* x  = (const float*)d_in[0];
    const float* W  = (const float*)d_in[1];
    const float* b  = (const float*)d_in[2];
    const float* A1 = (const float*)d_in[3];
    const float* B1 = (const float*)d_in[4];
    const float* A2 = (const float*)d_in[5];
    const float* B2 = (const float*)d_in[6];
    float* out = (float*)d_out;

    // Workspace: [x_bf16: 64 MB][Weff_bf16: 2 MB]
    __bf16* xb   = (__bf16*)d_ws;
    __bf16* Weff = (__bf16*)((char*)d_ws + (size_t)TOKENS * DIN * sizeof(__bf16));

    cvt_x_kernel<<<TOKENS * DIN / (256 * 8), 256, 0, stream>>>(x, xb);
    weff_kernel<<<DOUT * DIN / 256, 256, 0, stream>>>(W, A1, B1, A2, B2, Weff);
    gemm_bt_kernel<<<(TOKENS / BM) * (DOUT / BN), 512, 0, stream>>>(xb, Weff, b, out);
}

// Round 6
// 316.647 us; speedup vs baseline: 1.0545x; 1.0142x over previous
//
#include <hip/hip_runtime.h>

#define TOKENS 32768
#define DIN 1024
#define DOUT 1024
#define RANK 16
#define SCALE1 0.5f
#define SCALE2 1.0f

// R11: R10 (passing) with the barrier discipline relaxed to ONE barrier per
// phase. R10's [reads|BAR1|lgkm0|schedbar|MFMA|BAR2] globally separated LDS
// windows from MFMA windows -> serialization (LDS 2048cy + MFMA 2483cy per
// tile ~= observed 6300cy incl. overhead; MfmaUtil*dur == the 27.5us MFMA
// floor exactly). BAR1 was redundant: write-protection is carried by
// lgkm0->BAR2(p-1) (audited per region); tile RAW by vmcnt(8)+BAR. With C++
// ds_reads the compiler inserts fine-grained lgkmcnt before each MFMA, so
// sched_barrier(0)/manual pre-MFMA lgkm0 are dropped (m141: pinning hurts).
#define BM 256
#define BN 256
#define BK 64
#define KTILES (DIN / BK)  // 16

typedef __bf16 bf16x8 __attribute__((ext_vector_type(8)));
typedef float f32x4 __attribute__((ext_vector_type(4)));

// Async global->LDS, 16B per lane. LDS dest is wave-uniform base + lane*16.
__device__ __forceinline__ void load_lds16(const void* gptr, void* lptr) {
    __builtin_amdgcn_global_load_lds(
        (__attribute__((address_space(1))) void*)gptr,
        (__attribute__((address_space(3))) void*)lptr, 16, 0, 0);
}

// ---------------------------------------------------------------------------
// Kernel 1: Weff = W + 0.5*B1@A1 + 1.0*B2@A2, cast to bf16.  [DOUT, DIN]
// ---------------------------------------------------------------------------
__global__ void weff_kernel(const float* __restrict__ W, const float* __restrict__ A1,
                            const float* __restrict__ B1, const float* __restrict__ A2,
                            const float* __restrict__ B2, __bf16* __restrict__ Weff) {
    int idx = blockIdx.x * blockDim.x + threadIdx.x;  // over DOUT*DIN
    int o = idx >> 10;
    int i = idx & 1023;
    float s1 = 0.f, s2 = 0.f;
#pragma unroll
    for (int r = 0; r < RANK; ++r) {
        s1 += B1[o * RANK + r] * A1[r * DIN + i];
        s2 += B2[o * RANK + r] * A2[r * DIN + i];
    }
    Weff[idx] = (__bf16)(W[idx] + SCALE1 * s1 + SCALE2 * s2);
}

// ---------------------------------------------------------------------------
// Kernel 2: x fp32 -> bf16, 8 elems/thread, 16B stores. Streaming-bound ~30us;
// fusing into the GEMM exposed HBM latency on the critical path (R4: 250us).
// ---------------------------------------------------------------------------
__global__ void cvt_x_kernel(const float* __restrict__ x, __bf16* __restrict__ xb) {
    int i = (blockIdx.x * blockDim.x + threadIdx.x) * 8;
    float4 a = *(const float4*)(x + i);
    float4 b = *(const float4*)(x + i + 4);
    bf16x8 v;
    v[0] = (__bf16)a.x; v[1] = (__bf16)a.y; v[2] = (__bf16)a.z; v[3] = (__bf16)a.w;
    v[4] = (__bf16)b.x; v[5] = (__bf16)b.y; v[6] = (__bf16)b.z; v[7] = (__bf16)b.w;
    *(bf16x8*)(xb + i) = v;
}

// ---------------------------------------------------------------------------
// Kernel 3: out[M,N] = A[M,K] @ Bw[N,K]^T + bias.  256x256, BK=64, 8 waves.
//
// LDS half (128 rows x 64 bf16), quarters = 64-row sub-blocks. Row-major, 8
// chunks of 16B/row, phys_chunk = chunk ^ (row&7). gload_lds writes linearly
// (lane l -> row l>>3, phys chunk l&7 of its wave's 8-row slab), inverse
// swizzle on the per-lane GLOBAL source col; same XOR on ds_read side.
// Frag reads: phys chunk = (ksub*4 + lane>>4) ^ (lane&7): 0 conflicts
// (measured R6-R10).
//
// Snake phases per tile t (cur=t&1), B-frags held all tile:
//   ph0 (Alo,Blo): read A-lo(8)+B-lo(4);                   16 MFMA [0..3][0..1]
//   ph1 (Alo,Bhi): read B-hi(4); stage A q0,q2 (t+2,cur);  16 MFMA [0..3][2..3]
//   ph2 (Ahi,Bhi): read A-hi(8); stage B q0..q3 (t+2,cur); 16 MFMA [4..7][2..3]
//   ph3 (Ahi,Blo): no reads;     stage A q1,q3 (t+2,cur);  16 MFMA [4..7][0..1]
// Each phase: [reads|stages|setprio1 MFMA setprio0|lgkm0|BAR]. One barrier.
// WAR proof (single barrier): every wave's reads of a region are lgkm0-
// complete before it passes that phase's BAR; stages of that region are
// issued only after that BAR -> no overwrite of live data. Quarter-by-
// quarter: A q0,q2 freed @BAR(ph0), staged ph1; B q0..q3 freed @BAR(ph1),
// staged ph2; A q1,q3 freed @BAR(ph2), staged ph3.
// Ledger: enter t with t+1's 8 outstanding; +8 (t+2) during t; ph3 ends
// vmcnt(8)+BAR (drains t+1's 8, issued 5-7 phases earlier). Prologue:
// tile0(8)+tile1(8), vmcnt(8). Tail: t=14 vmcnt(0), t=15 bare.
// ---------------------------------------------------------------------------
__global__ __launch_bounds__(512, 2) void gemm_bt_kernel(
    const __bf16* __restrict__ A,   // [TOKENS, DIN] bf16
    const __bf16* __restrict__ Bw,  // [DOUT, DIN] bf16
    const float* __restrict__ bias, float* __restrict__ C) {
    __shared__ alignas(16) __bf16 lsA[2][2][128 * BK];  // [buf][half] 2x2x16KB
    __shared__ alignas(16) __bf16 lsB[2][2][128 * BK];  // total 128 KiB

    const int tid = threadIdx.x;
    const int wave = tid >> 6;
    const int lane = tid & 63;

    // XCD-aware swizzle: 512 blocks = 8 xcds x 64 (bijective). Within an xcd:
    // 16 m-tiles x 4 n-tiles, n fastest -> Weff (2MB) L2-resident per xcd.
    const int l = blockIdx.x;
    const int xcd = l & 7;
    const int s = l >> 3;
    const int m0 = (xcd * 16 + (s >> 2)) * BM;
    const int n0 = (s & 3) * BN;

    const int wm = wave >> 2;  // 0..1  (M half: 128 rows)
    const int wn = wave & 3;   // 0..3  (N quarter: 64 cols)

    // Staging: one call = one wave = one 8-row x 64-col slab (1KB) of a
    // quarter. lane l: row l>>3, phys chunk l&7 <- logical (l&7)^(l>>3).
    const int srow = lane >> 3;
    const int scol = ((lane & 7) ^ srow) * 8;  // pre-swizzled source col
    const __bf16* gA = A + (size_t)(m0 + wave * 8 + srow) * DIN + scol;
    const __bf16* gB = Bw + (size_t)(n0 + wave * 8 + srow) * DIN + scol;
    const int sdst = wave * 512;  // elem offset of wave's slab within quarter

    // Quarter q (global rows q*64..q*64+63) = half q>>1, local rows (q&1)*64+.
#define STG_A_Q(buf, q, kk) \
    load_lds16(gA + (size_t)(q) * 64 * DIN + (kk), &lsA[buf][(q) >> 1][((q) & 1) * 4096 + sdst])
#define STG_B_Q(buf, q, kk) \
    load_lds16(gB + (size_t)(q) * 64 * DIN + (kk), &lsB[buf][(q) >> 1][((q) & 1) * 4096 + sdst])

    // Fragment addressing: row ≡ lane&15 (mod 16); phys chunk =
    // (ksub*4 + lane>>4) ^ (lane&7). Row offsets mult of 16 -> row&7==lane&7.
    const int frow = lane & 15;
    const int fc0 = ((lane >> 4) ^ (lane & 7)) * 8;        // ksub=0
    const int fc1 = ((4 + (lane >> 4)) ^ (lane & 7)) * 8;  // ksub=1

    f32x4 acc[8][4];
#pragma unroll
    for (int i = 0; i < 8; ++i)
#pragma unroll
        for (int j = 0; j < 4; ++j) acc[i][j] = f32x4{0.f, 0.f, 0.f, 0.f};

    // Prologue: tile0 -> buf0 (8 loads), tile1 -> buf1 (8 loads), wait tile0.
#pragma unroll
    for (int q = 0; q < 4; ++q) { STG_A_Q(0, q, 0); STG_B_Q(0, q, 0); }
#pragma unroll
    for (int q = 0; q < 4; ++q) { STG_A_Q(1, q, BK); STG_B_Q(1, q, BK); }
    asm volatile("s_waitcnt vmcnt(8)\n\ts_barrier" ::: "memory");

#pragma unroll 2
    for (int t = 0; t < KTILES; ++t) {
        const int cur = t & 1;
        const int kn2 = (t + 2) * BK;
        const __bf16* baseA = &lsA[cur][wm][0];
        const __bf16* baseB = &lsB[cur][wn >> 1][(wn & 1) * (64 * BK)];
        bf16x8 af[4][2], bf[4][2];

        // -------- ph0: (A-lo, B-lo); no staging --------
#pragma unroll
        for (int i = 0; i < 4; ++i) {
            const int ro = (i * 16 + frow) * BK;
            af[i][0] = *(const bf16x8*)&baseA[ro + fc0];
            af[i][1] = *(const bf16x8*)&baseA[ro + fc1];
        }
#pragma unroll
        for (int j = 0; j < 2; ++j) {
            const int ro = (j * 16 + frow) * BK;
            bf[j][0] = *(const bf16x8*)&baseB[ro + fc0];
            bf[j][1] = *(const bf16x8*)&baseB[ro + fc1];
        }
        __builtin_amdgcn_s_setprio(1);
#pragma unroll
        for (int i = 0; i < 4; ++i)
#pragma unroll
            for (int j = 0; j < 2; ++j) {
                acc[i][j] = __builtin_amdgcn_mfma_f32_16x16x32_bf16(
                    af[i][0], bf[j][0], acc[i][j], 0, 0, 0);
                acc[i][j] = __builtin_amdgcn_mfma_f32_16x16x32_bf16(
                    af[i][1], bf[j][1], acc[i][j], 0, 0, 0);
            }
        __builtin_amdgcn_s_setprio(0);
        asm volatile("s_waitcnt lgkmcnt(0)" ::: "memory");
        asm volatile("s_barrier" ::: "memory");

        // -------- ph1: (A-lo, B-hi); stage A q0,q2 of t+2 (freed @BAR ph0) --
#pragma unroll
        for (int j = 2; j < 4; ++j) {
            const int ro = (j * 16 + frow) * BK;
            bf[j][0] = *(const bf16x8*)&baseB[ro + fc0];
            bf[j][1] = *(const bf16x8*)&baseB[ro + fc1];
        }
        if (t + 2 < KTILES) { STG_A_Q(cur, 0, kn2); STG_A_Q(cur, 2, kn2); }
        __builtin_amdgcn_s_setprio(1);
#pragma unroll
        for (int i = 0; i < 4; ++i)
#pragma unroll
            for (int j = 2; j < 4; ++j) {
                acc[i][j] = __builtin_amdgcn_mfma_f32_16x16x32_bf16(
                    af[i][0], bf[j][0], acc[i][j], 0, 0, 0);
                acc[i][j] = __builtin_amdgcn_mfma_f32_16x16x32_bf16(
                    af[i][1], bf[j][1], acc[i][j], 0, 0, 0);
            }
        __builtin_amdgcn_s_setprio(0);
        asm volatile("s_waitcnt lgkmcnt(0)" ::: "memory");
        asm volatile("s_barrier" ::: "memory");

        // -------- ph2: (A-hi, B-hi); stage B q0..q3 of t+2 (freed @BAR ph1) -
#pragma unroll
        for (int i = 0; i < 4; ++i) {
            const int ro = ((4 + i) * 16 + frow) * BK;
            af[i][0] = *(const bf16x8*)&baseA[ro + fc0];
            af[i][1] = *(const bf16x8*)&baseA[ro + fc1];
        }
        if (t + 2 < KTILES) {
            STG_B_Q(cur, 0, kn2); STG_B_Q(cur, 1, kn2);
            STG_B_Q(cur, 2, kn2); STG_B_Q(cur, 3, kn2);
        }
        __builtin_amdgcn_s_setprio(1);
#pragma unroll
        for (int i = 0; i < 4; ++i)
#pragma unroll
            for (int j = 2; j < 4; ++j) {
                acc[4 + i][j] = __builtin_amdgcn_mfma_f32_16x16x32_bf16(
                    af[i][0], bf[j][0], acc[4 + i][j], 0, 0, 0);
                acc[4 + i][j] = __builtin_amdgcn_mfma_f32_16x16x32_bf16(
                    af[i][1], bf[j][1], acc[4 + i][j], 0, 0, 0);
            }
        __builtin_amdgcn_s_setprio(0);
        asm volatile("s_waitcnt lgkmcnt(0)" ::: "memory");
        asm volatile("s_barrier" ::: "memory");

        // -------- ph3: (A-hi, B-lo); stage A q1,q3 of t+2 (freed @BAR ph2) --
        if (t + 2 < KTILES) { STG_A_Q(cur, 1, kn2); STG_A_Q(cur, 3, kn2); }
        __builtin_amdgcn_s_setprio(1);
#pragma unroll
        for (int i = 0; i < 4; ++i)
#pragma unroll
            for (int j = 0; j < 2; ++j) {
                acc[4 + i][j] = __builtin_amdgcn_mfma_f32_16x16x32_bf16(
                    af[i][0], bf[j][0], acc[4 + i][j], 0, 0, 0);
                acc[4 + i][j] = __builtin_amdgcn_mfma_f32_16x16x32_bf16(
                    af[i][1], bf[j][1], acc[4 + i][j], 0, 0, 0);
            }
        __builtin_amdgcn_s_setprio(0);
        if (t < KTILES - 2) {
            asm volatile("s_waitcnt vmcnt(8)\n\ts_barrier" ::: "memory");
        } else if (t == KTILES - 2) {
            asm volatile("s_waitcnt vmcnt(0)\n\ts_barrier" ::: "memory");
        }
        // t == KTILES-1: fall through to epilogue.
    }
#undef STG_A_Q
#undef STG_B_Q

    // Epilogue: C/D layout col = lane&15 (n), row = (lane>>4)*4 + reg (m).
    const int rbase = (lane >> 4) * 4;
#pragma unroll
    for (int nt = 0; nt < 4; ++nt) {
        const int n = n0 + wn * 64 + nt * 16 + frow;
        const float bv = bias[n];
#pragma unroll
        for (int mt = 0; mt < 8; ++mt) {
            const int m = m0 + wm * 128 + mt * 16 + rbase;
            float* cp = C + (size_t)m * DOUT + n;
#pragma unroll
            for (int r = 0; r < 4; ++r) cp[(size_t)r * DOUT] = acc[mt][nt][r] + bv;
        }
    }
}

// ---------------------------------------------------------------------------
extern "C" void kernel_launch(void* const* d_in, const int* in_sizes, int n_in,
                              void* d_out, int out_size, void* d_ws, size_t ws_size,
                              hipStream_t stream) {
    const float* x  = (const float*)d_in[0];
    const float* W  = (const float*)d_in[1];
    const float* b  = (const float*)d_in[2];
    const float* A1 = (const float*)d_in[3];
    const float* B1 = (const float*)d_in[4];
    const float* A2 = (const float*)d_in[5];
    const float* B2 = (const float*)d_in[6];
    float* out = (float*)d_out;

    // Workspace: [x_bf16: 64 MB][Weff_bf16: 2 MB]
    __bf16* xb   = (__bf16*)d_ws;
    __bf16* Weff = (__bf16*)((char*)d_ws + (size_t)TOKENS * DIN * sizeof(__bf16));

    cvt_x_kernel<<<TOKENS * DIN / (256 * 8), 256, 0, stream>>>(x, xb);
    weff_kernel<<<DOUT * DIN / 256, 256, 0, stream>>>(W, A1, B1, A2, B2, Weff);
    gemm_bt_kernel<<<(TOKENS / BM) * (DOUT / BN), 512, 0, stream>>>(xb, Weff, b, out);
}